// Round 13
// baseline (4353.457 us; speedup 1.0000x reference)
//
#include <hip/hip_runtime.h>

typedef _Float16 half_t;
typedef _Float16 half8 __attribute__((ext_vector_type(8)));
typedef _Float16 half4 __attribute__((ext_vector_type(4)));
typedef _Float16 half2 __attribute__((ext_vector_type(2)));
typedef float f32x4 __attribute__((ext_vector_type(4)));
typedef float f32x2 __attribute__((ext_vector_type(2)));

// ---------------- fp32 [K][N] -> fp16 [N rows][ldo] transpose (col offset) ---
__global__ void wt_transpose(const float* __restrict__ in, half_t* __restrict__ outp,
                             int K, int N, int ldo, int co) {
  __shared__ float tile[32][33];
  int nb = blockIdx.x * 32, kb = blockIdx.y * 32;
  int tx = threadIdx.x, ty = threadIdx.y;  // 32 x 8
  for (int i = ty; i < 32; i += 8)
    tile[i][tx] = in[(size_t)(kb + i) * N + nb + tx];
  __syncthreads();
  for (int i = ty; i < 32; i += 8)
    outp[(size_t)(nb + i) * ldo + co + kb + tx] = (half_t)tile[tx][i];
}

// ---------------- embedding gather -> fp16 row-major [m=s*64+b][256] ---------
__global__ __launch_bounds__(256) void embed_kernel(const int* __restrict__ x,
    const float* __restrict__ emb, half_t* __restrict__ E) {
  int g = blockIdx.x * 256 + threadIdx.x;  // 0 .. 32768*32-1
  int m = g >> 5, dp = g & 31;
  int b = m & 63, s = m >> 6;
  int tok = x[b * 512 + s];
  const float* src = emb + (size_t)tok * 256 + dp * 8;
  half8 v;
  #pragma unroll
  for (int i = 0; i < 8; ++i) v[i] = (half_t)src[i];
  *(half8*)(E + (size_t)m * 256 + dp * 8) = v;
}

// ---------------- 128x128 fp16 MFMA GEMM, fp32 C row-major -------------------
__global__ __launch_bounds__(256)
void gemm128(const half_t* __restrict__ A, const half_t* __restrict__ BT,
             float* __restrict__ C, int N, int K) {
  __shared__ __align__(16) half_t As[128 * 32];
  __shared__ __align__(16) half_t Bs[128 * 32];
  const int tid = threadIdx.x;
  const int lane = tid & 63, wid = tid >> 6;
  const int wm = wid >> 1, wn = wid & 1;
  const int l15 = lane & 15, l4 = lane >> 4;
  const int bm = blockIdx.y * 128, bn = blockIdx.x * 128;
  const int srow = tid >> 2;
  const int skb = (tid & 3) * 8;
  f32x4 acc[4][4] = {};

  half8 va[2], vb[2];
  #pragma unroll
  for (int c = 0; c < 2; ++c) {
    int row = c * 64 + srow;
    va[c] = *(const half8*)(A + (size_t)(bm + row) * K + skb);
    vb[c] = *(const half8*)(BT + (size_t)(bn + row) * K + skb);
  }
  for (int k0 = 0; k0 < K; k0 += 32) {
    __syncthreads();
    #pragma unroll
    for (int c = 0; c < 2; ++c) {
      int row = c * 64 + srow;
      *(half8*)(As + row * 32 + skb) = va[c];
      *(half8*)(Bs + row * 32 + skb) = vb[c];
    }
    __syncthreads();
    int k1 = k0 + 32;
    if (k1 < K) {
      #pragma unroll
      for (int c = 0; c < 2; ++c) {
        int row = c * 64 + srow;
        va[c] = *(const half8*)(A + (size_t)(bm + row) * K + k1 + skb);
        vb[c] = *(const half8*)(BT + (size_t)(bn + row) * K + k1 + skb);
      }
    }
    half8 af[4], bf[4];
    #pragma unroll
    for (int mt = 0; mt < 4; ++mt)
      af[mt] = *(const half8*)(As + (wm * 64 + mt * 16 + l15) * 32 + l4 * 8);
    #pragma unroll
    for (int nt = 0; nt < 4; ++nt)
      bf[nt] = *(const half8*)(Bs + (wn * 64 + nt * 16 + l15) * 32 + l4 * 8);
    #pragma unroll
    for (int mt = 0; mt < 4; ++mt)
      #pragma unroll
      for (int nt = 0; nt < 4; ++nt)
        acc[mt][nt] = __builtin_amdgcn_mfma_f32_16x16x32_f16(af[mt], bf[nt], acc[mt][nt], 0, 0, 0);
  }
  #pragma unroll
  for (int mt = 0; mt < 4; ++mt)
    #pragma unroll
    for (int nt = 0; nt < 4; ++nt) {
      int col = bn + wn * 64 + nt * 16 + l15;
      int row0 = bm + wm * 64 + mt * 16 + l4 * 4;
      #pragma unroll
      for (int r = 0; r < 4; ++r)
        C[(size_t)(row0 + r) * N + col] = acc[mt][nt][r];
    }
}

// ---------------- fused 2-layer persistent GRU recurrence --------------------
// Same data plan as rounds 7-12. NEW: PER-WAVE flags. flags0[64 WG][4 wave]
// (16B stride): wave wv of L0 WG w posts flags0[w*4+wv]=e+1 right after ITS
// OWN publish stores drain (vmcnt is per-wave) -- no cross-wave wait, no
// barrier before the flag. flags1[128 WG][4 wave] likewise (value e).
// Consumers poll exactly the producer-wave set they consume:
//   L0 data: group's 128 wave-flags >= e (2/lane) + WAR flags1 waves 0,1 of
//            group's 64 L1 WGs >= e-5 (2/lane), all in ONE 4-load asm round.
//   L1 wv<2: the 64 wave-flags of the L0 half it loads >= e (1/lane).
//   L1 wv>=2: group L1 wave-flags >= e-1 (2/lane).
// L0's end-of-loop barrier is REMOVED: its data poll includes own-WG wave
// flags (posted only after combine), so no wave can reach epoch e+1's scatter
// before all own-WG waves finished epoch e's combine; S2 barrier counts stay
// aligned. L1 keeps its end barrier. Deadman 2^14 on all spins.
#define MF(af, bf, a) a = __builtin_amdgcn_mfma_f32_16x16x32_f16(af, bf, a, 0, 0, 0)
#define BC8(x) __builtin_bit_cast(half8, x)
#define GLD4(dst, base, OFS) asm volatile("global_load_dwordx4 %0, %1, off offset:" OFS " sc0 sc1" : "=v"(dst) : "v"(base))
#define GLD4P(dst, base, OFS) asm volatile("global_load_dwordx4 %0, %1, off offset:" OFS : "=v"(dst) : "v"(base))
#define HL8(t, B) GLD4(hrA[t][0],B,"0");GLD4(hrA[t][1],B,"64");GLD4(hrA[t][2],B,"128");GLD4(hrA[t][3],B,"192");GLD4(hrA[t][4],B,"256");GLD4(hrA[t][5],B,"320");GLD4(hrA[t][6],B,"384");GLD4(hrA[t][7],B,"448")
#define HL16(t, B) HL8(t,B);GLD4(hrA[t][8],B,"512");GLD4(hrA[t][9],B,"576");GLD4(hrA[t][10],B,"640");GLD4(hrA[t][11],B,"704");GLD4(hrA[t][12],B,"768");GLD4(hrA[t][13],B,"832");GLD4(hrA[t][14],B,"896");GLD4(hrA[t][15],B,"960")
#define LDH0(u, kt) (*(const half8*)(smem + ((((u) * 2048) + wv * 512 + (kt) * 64 + l4x16) ^ (((u) & 7) << 4))))
#define LDE0(u, kt) (*(const half8*)(smem + 65536 + ((((u) * 512) + wv * 128 + (kt) * 64 + l4x16) ^ (((u) & 7) << 4))))
#define LDH1(kt) (*(const half8*)(smem + ((l15 * 4096 + wv * 1024 + (kt) * 64 + l4x16) ^ ((l15 & 7) << 4))))
#define SB __builtin_amdgcn_sched_barrier(0)

__global__ __launch_bounds__(256, 1)
void recur_fused(const half_t* __restrict__ E16,  // [32768][256]
                 const half_t* __restrict__ T0,   // [3072][1280] = [U0;W0]^T
                 const half_t* __restrict__ T1,   // [3072][2048] = [W1;U1]^T
                 const float* __restrict__ bias0, // [2][3072]
                 const float* __restrict__ bias1, // [2][3072]
                 half_t* __restrict__ ys1,        // [32768][1024]
                 half_t* __restrict__ h0f,        // [6][64][1024] half
                 half_t* __restrict__ h1f,        // [4][64][1024] half
                 int* __restrict__ flags0,        // [64 WG][4 wave][4] (16B stride)
                 int* __restrict__ flags1) {      // [128 WG][4 wave][4]
  extern __shared__ unsigned char smem[];
  const int tid = threadIdx.x;
  const int lane = tid & 63, wv = tid >> 6;
  const int l15 = lane & 15, l4 = lane >> 4;
  const int l4x16 = l4 * 16;
  const int ug = tid >> 5;          // 0..7
  const int bl = lane & 31;         // batch within group

  if (blockIdx.x < 64) {
    // =================== LAYER 0 ===================
    const int w = blockIdx.x;
    const int g = w >> 5, uslot = w & 31, j0 = uslot * 32;
    float* hgp = (float*)(smem + 81920);   // [4][32][129]

    // stage h-part hh rows (32 units x 1024), XOR-swizzled
    for (int it = 0; it < 16; ++it) {
      int idx = it * 256 + tid;
      int u = idx >> 7, kc = idx & 127;
      int byteoff = (u * 2048 + kc * 16) ^ ((u & 7) << 4);
      *(half8*)(smem + byteoff) =
          *(const half8*)(T0 + (size_t)(2048 + j0 + u) * 1280 + kc * 8);
    }
    // stage e-part hh rows (32 units x 256)
    for (int it = 0; it < 4; ++it) {
      int idx = it * 256 + tid;
      int u = idx >> 5, kc = idx & 31;
      int byteoff = 65536 + ((u * 512 + kc * 16) ^ ((u & 7) << 4));
      *(half8*)(smem + byteoff) =
          *(const half8*)(T0 + (size_t)(2048 + j0 + u) * 1280 + 1024 + kc * 8);
    }
    // pin z,r B-frags: h-part and e-part
    half8 zr[2][2][8], ezr[2][2][2];
    #pragma unroll
    for (int gate = 0; gate < 2; ++gate)
      #pragma unroll
      for (int uh = 0; uh < 2; ++uh) {
        const half_t* row = T0 + (size_t)(gate * 1024 + j0 + uh * 16 + l15) * 1280;
        #pragma unroll
        for (int kt = 0; kt < 8; ++kt)
          zr[gate][uh][kt] = *(const half8*)(row + wv * 256 + kt * 32 + l4 * 8);
        #pragma unroll
        for (int kt = 0; kt < 2; ++kt)
          ezr[gate][uh][kt] = *(const half8*)(row + 1024 + wv * 64 + kt * 32 + l4 * 8);
      }
    // gate constants + master h in regs
    float bz[4], br[4], bhr[4], bxh[4], hM[4];
    #pragma unroll
    for (int q = 0; q < 4; ++q) {
      int j = j0 + ug * 4 + q;
      bz[q]  = bias0[j]        + bias0[3072 + j];
      br[q]  = bias0[1024 + j] + bias0[4096 + j];
      bxh[q] = bias0[2048 + j];
      bhr[q] = bias0[5120 + j];
      hM[q] = 0.f;
    }
    // per-wave flag poll pointers: data = group's 128 wave-flags (2/lane);
    // WAR = waves 0,1 of group's 64 L1 WGs (2/lane)
    const int* pda = flags0 + (g * 128 + lane) * 4;
    const int* pdb = flags0 + (g * 128 + 64 + lane) * 4;
    const int* pwa = flags1 + ((g * 64 + lane) * 4 + 0) * 4;
    const int* pwb = flags1 + ((g * 64 + lane) * 4 + 1) * 4;
    int fda = 0, fdb = 0, fwa = 0, fwb = 0;
    // E16 prefetch for epoch 0 (plain loads; double-buffered across epochs)
    f32x4 erC[2][2], erN[2][2];
    {
      const char* eb0 = (const char*)E16 + (size_t)(g * 32 + l15) * 512 + wv * 128 + l4x16;
      const char* eb1 = eb0 + 8192;
      GLD4P(erC[0][0], eb0, "0"); GLD4P(erC[0][1], eb0, "64");
      GLD4P(erC[1][0], eb1, "0"); GLD4P(erC[1][1], eb1, "64");
    }
    asm volatile("s_waitcnt vmcnt(0)" ::: "memory");
    __syncthreads();

    for (int e = 0; e < 512; ++e) {
      // combined poll: data >= e AND WAR >= e-5 (cached; 1 asm round/retry)
      {
        int dm = 0;
        while (!__all((fda >= e) & (fdb >= e) & (fwa >= e - 5) & (fwb >= e - 5))) {
          asm volatile(
            "global_load_dword %0, %4, off sc0 sc1\n\t"
            "global_load_dword %1, %5, off sc0 sc1\n\t"
            "global_load_dword %2, %6, off sc0 sc1\n\t"
            "global_load_dword %3, %7, off sc0 sc1\n\t"
            "s_waitcnt vmcnt(0)"
            : "=v"(fda), "=v"(fdb), "=v"(fwa), "=v"(fwb)
            : "v"(pda), "v"(pdb), "v"(pwa), "v"(pwb)
            : "memory");
          if (++dm > (1 << 14)) break;
        }
      }
      // A loads: h0[e-1] (buf (e+5)%6, sc forced-miss); E16[e] in erC;
      // E16[e+1] prefetch issued last (newest in vmcnt order).
      f32x4 hrA[2][8];
      {
        const char* hbb = (const char*)h0f + (size_t)((e + 5) % 6) * 131072;
        const char* hb0 = hbb + (g * 32 + l15) * 2048 + wv * 512 + l4x16;
        const char* hb1 = hb0 + 32768;
        HL8(0, hb0); HL8(1, hb1);
        int en = (e < 511) ? e + 1 : e;
        const char* eb0 = (const char*)E16 +
            (size_t)(en * 64 + g * 32 + l15) * 512 + wv * 128 + l4x16;
        const char* eb1 = eb0 + 8192;
        GLD4P(erN[0][0], eb0, "0"); GLD4P(erN[0][1], eb0, "64");
        GLD4P(erN[1][0], eb1, "0"); GLD4P(erN[1][1], eb1, "64");
      }
      // ---- MFMA phase 1: A-tile 0 (oldest 8 loads; 12 in flight allowed) ----
      asm volatile("s_waitcnt vmcnt(12)" ::: "memory"); SB;
      __builtin_amdgcn_s_setprio(1);
      f32x4 acc[2][8] = {};
      #pragma unroll
      for (int kt = 0; kt < 8; ++kt) {
        half8 af0 = BC8(hrA[0][kt]);
        MF(af0, zr[0][0][kt], acc[0][0]);
        MF(af0, zr[0][1][kt], acc[0][1]);
        MF(af0, zr[1][0][kt], acc[0][2]);
        MF(af0, zr[1][1][kt], acc[0][3]);
        half8 bh0 = LDH0(l15, kt), bh1 = LDH0(16 + l15, kt);
        MF(af0, bh0, acc[0][4]);
        MF(af0, bh1, acc[0][5]);
      }
      // ---- MFMA phase 2: A-tile 1 (all h loads done; erN may be in flight) --
      asm volatile("s_waitcnt vmcnt(4)" ::: "memory"); SB;
      #pragma unroll
      for (int kt = 0; kt < 8; ++kt) {
        half8 af1 = BC8(hrA[1][kt]);
        MF(af1, zr[0][0][kt], acc[1][0]);
        MF(af1, zr[0][1][kt], acc[1][1]);
        MF(af1, zr[1][0][kt], acc[1][2]);
        MF(af1, zr[1][1][kt], acc[1][3]);
        half8 bh0 = LDH0(l15, kt), bh1 = LDH0(16 + l15, kt);
        MF(af1, bh0, acc[1][4]);
        MF(af1, bh1, acc[1][5]);
      }
      // ---- MFMA phase 3: e-part (erC from regs; drain erN for rotation) ----
      asm volatile("s_waitcnt vmcnt(0)" ::: "memory"); SB;
      #pragma unroll
      for (int kt = 0; kt < 2; ++kt) {
        half8 af0 = BC8(erC[0][kt]), af1 = BC8(erC[1][kt]);
        MF(af0, ezr[0][0][kt], acc[0][0]); MF(af1, ezr[0][0][kt], acc[1][0]);
        MF(af0, ezr[0][1][kt], acc[0][1]); MF(af1, ezr[0][1][kt], acc[1][1]);
        MF(af0, ezr[1][0][kt], acc[0][2]); MF(af1, ezr[1][0][kt], acc[1][2]);
        MF(af0, ezr[1][1][kt], acc[0][3]); MF(af1, ezr[1][1][kt], acc[1][3]);
        half8 be0 = LDE0(l15, kt), be1 = LDE0(16 + l15, kt);
        MF(af0, be0, acc[0][6]); MF(af1, be0, acc[1][6]);
        MF(af0, be1, acc[0][7]); MF(af1, be1, acc[1][7]);
      }
      __builtin_amdgcn_s_setprio(0);
      // scatter partials: rows = kv*32 + batch, cols: z0..31|r|hh_h|hh_e
      #pragma unroll
      for (int m = 0; m < 2; ++m)
        #pragma unroll
        for (int n = 0; n < 8; ++n) {
          int colb = (n < 6) ? ((n >> 1) * 32 + (n & 1) * 16) : (96 + (n & 1) * 16);
          #pragma unroll
          for (int r = 0; r < 4; ++r)
            hgp[(wv * 32 + m * 16 + l4 * 4 + r) * 129 + colb + l15] = acc[m][n][r];
        }
      __syncthreads();  // S2: partials visible for combine
      // combine (thread = batch bl x 4 units)
      half4 hv;
      #pragma unroll
      for (int q = 0; q < 4; ++q) {
        int c = ug * 4 + q;
        float hz = 0.f, hr = 0.f, hhh = 0.f, xh = 0.f;
        #pragma unroll
        for (int kv = 0; kv < 4; ++kv) {
          const float* rowp = hgp + (kv * 32 + bl) * 129 + c;
          hz += rowp[0]; hr += rowp[32]; hhh += rowp[64]; xh += rowp[96];
        }
        float z = 1.f / (1.f + __expf(-(hz + bz[q])));
        float r = 1.f / (1.f + __expf(-(hr + br[q])));
        float targ = xh + bxh[q] + r * (hhh + bhr[q]);
        float hh = 1.f - 2.f / (1.f + __expf(2.f * targ));
        float hnew = z * hM[q] + (1.f - z) * hh;
        hM[q] = hnew;
        hv[q] = (half_t)hnew;
      }
      // rotate E16 buffers (erN drained at phase-3 vmcnt(0))
      #pragma unroll
      for (int a = 0; a < 2; ++a)
        #pragma unroll
        for (int b2 = 0; b2 < 2; ++b2) erC[a][b2] = erN[a][b2];
      // publish h0[e] -> buf e%6, then per-wave drain + per-wave flag.
      // No end barrier: the data poll includes own-WG wave flags, which are
      // posted only after combine -> epoch e+1's scatter cannot race epoch e.
      {
        const char* dst = (const char*)h0f + (size_t)(e % 6) * 131072
                        + (g * 32 + bl) * 2048 + (j0 + ug * 4) * 2;
        f32x2 pv = __builtin_bit_cast(f32x2, hv);
        asm volatile("global_store_dwordx2 %0, %1, off sc0 sc1"
                     :: "v"(dst), "v"(pv) : "memory");
      }
      asm volatile("s_waitcnt vmcnt(0)" ::: "memory");
      if (lane == 0) {
        int tv = e + 1;
        const int* dst = flags0 + (w * 4 + wv) * 4;
        asm volatile("global_store_dword %0, %1, off sc0 sc1"
                     :: "v"(dst), "v"(tv) : "memory");
      }
    }
  } else {
    // =================== LAYER 1 ===================
    const int wp = blockIdx.x - 64;
    const int g = wp >> 6, uslot = wp & 63, j0 = uslot * 16;
    float* hgp = (float*)(smem + 65536);   // [4][32][65]

    // stage hh rows (16 units x 2048), XOR-swizzled
    for (int it = 0; it < 16; ++it) {
      int idx = it * 256 + tid;
      int u = idx >> 8, kc = idx & 255;
      int byteoff = (u * 4096 + kc * 16) ^ ((u & 7) << 4);
      *(half8*)(smem + byteoff) =
          *(const half8*)(T1 + (size_t)(2048 + j0 + u) * 2048 + kc * 8);
    }
    // pin z,r B-frags over this wave's 512-k slice
    half8 zr1[2][16];
    #pragma unroll
    for (int gate = 0; gate < 2; ++gate) {
      const half_t* row = T1 + (size_t)(gate * 1024 + j0 + l15) * 2048 + wv * 512;
      #pragma unroll
      for (int kt = 0; kt < 16; ++kt)
        zr1[gate][kt] = *(const half8*)(row + kt * 32 + l4 * 8);
    }
    float bz[2], br[2], bhr[2], bxh[2], hM[2];
    #pragma unroll
    for (int q = 0; q < 2; ++q) {
      int j = j0 + ug * 2 + q;
      bz[q]  = bias1[j]        + bias1[3072 + j];
      br[q]  = bias1[1024 + j] + bias1[4096 + j];
      bxh[q] = bias1[2048 + j];
      bhr[q] = bias1[5120 + j];
      hM[q] = 0.f;
    }
    // poll pointers: wv<2 -> exactly the 64 L0 wave-flags of the half this
    // wave loads (1/lane); wv>=2 -> group L1 wave-flags (2/lane)
    const int* pd = flags0 + (g * 128 + wv * 64 + lane) * 4;
    const int wvx = (wv >= 2) ? (wv - 2) : 0;
    const int pairbase = g * 256 + (wvx * 64 + lane) * 2;
    const int* ps0 = flags1 + pairbase * 4;
    const int* ps1 = flags1 + (pairbase + 1) * 4;
    int fd = 0, fs0 = 0, fs1 = 0;
    __syncthreads();

    for (int e = 1; e <= 512; ++e) {
      if (wv < 2) {
        int dm = 0;
        while (!__all(fd >= e)) {
          asm volatile("global_load_dword %0, %1, off sc0 sc1\n\ts_waitcnt vmcnt(0)"
                       : "=v"(fd) : "v"(pd) : "memory");
          if (++dm > (1 << 14)) break;
        }
      } else {
        int dm = 0;
        while (!__all((fs0 >= e - 1) & (fs1 >= e - 1))) {
          asm volatile(
            "global_load_dword %0, %2, off sc0 sc1\n\t"
            "global_load_dword %1, %3, off sc0 sc1\n\t"
            "s_waitcnt vmcnt(0)"
            : "=v"(fs0), "=v"(fs1) : "v"(ps0), "v"(ps1) : "memory");
          if (++dm > (1 << 14)) break;
        }
      }
      // A loads: waves 0,1 from h0[e-1] (buf (e+5)%6); waves 2,3 from h1[e-2]
      f32x4 hrA[2][16];
      {
        const char* fb = (wv < 2)
            ? (const char*)h0f + (size_t)((e + 5) % 6) * 131072
            : (const char*)h1f + (size_t)((e + 2) & 3) * 131072;
        const char* b0 = fb + (g * 32 + l15) * 2048 + (wv & 1) * 1024 + l4x16;
        const char* b1 = b0 + 32768;
        HL16(0, b0); HL16(1, b1);
      }
      // ---- MFMA phase 1: A-tile 0 (oldest 16 loads) ----
      asm volatile("s_waitcnt vmcnt(16)" ::: "memory"); SB;
      __builtin_amdgcn_s_setprio(1);
      f32x4 acc[2][3] = {};
      #pragma unroll
      for (int kt = 0; kt < 16; ++kt) {
        half8 af0 = BC8(hrA[0][kt]);
        MF(af0, zr1[0][kt], acc[0][0]);
        MF(af0, zr1[1][kt], acc[0][1]);
        half8 bh = LDH1(kt);
        MF(af0, bh, acc[0][2]);
      }
      // ---- MFMA phase 2: A-tile 1 ----
      asm volatile("s_waitcnt vmcnt(0)" ::: "memory"); SB;
      #pragma unroll
      for (int kt = 0; kt < 16; ++kt) {
        half8 af1 = BC8(hrA[1][kt]);
        MF(af1, zr1[0][kt], acc[1][0]);
        MF(af1, zr1[1][kt], acc[1][1]);
        half8 bh = LDH1(kt);
        MF(af1, bh, acc[1][2]);
      }
      __builtin_amdgcn_s_setprio(0);
      // scatter: cols z:0..15, r:16..31, hh_h:32..47 (wv>=2), hh_x:48..63 (wv<2)
      {
        int hhcol = (wv < 2) ? 48 : 32;
        #pragma unroll
        for (int m = 0; m < 2; ++m)
          #pragma unroll
          for (int r = 0; r < 4; ++r) {
            int row = (wv * 32 + m * 16 + l4 * 4 + r) * 65;
            hgp[row + l15]        = acc[m][0][r];
            hgp[row + 16 + l15]   = acc[m][1][r];
            hgp[row + hhcol + l15] = acc[m][2][r];
          }
      }
      __syncthreads();
      // combine (thread = batch bl x 2 units)
      half2 hv;
      #pragma unroll
      for (int q = 0; q < 2; ++q) {
        int c = ug * 2 + q;
        float hz = 0.f, hr = 0.f;
        #pragma unroll
        for (int kv = 0; kv < 4; ++kv) {
          const float* rowp = hgp + (kv * 32 + bl) * 65 + c;
          hz += rowp[0]; hr += rowp[16];
        }
        float hhh = hgp[(2 * 32 + bl) * 65 + 32 + c] + hgp[(3 * 32 + bl) * 65 + 32 + c];
        float xh  = hgp[(0 * 32 + bl) * 65 + 48 + c] + hgp[(1 * 32 + bl) * 65 + 48 + c];
        float z = 1.f / (1.f + __expf(-(hz + bz[q])));
        float r = 1.f / (1.f + __expf(-(hr + br[q])));
        float targ = xh + bxh[q] + r * (hhh + bhr[q]);
        float hh = 1.f - 2.f / (1.f + __expf(2.f * targ));
        float hnew = z * hM[q] + (1.f - z) * hh;
        hM[q] = hnew;
        hv[q] = (half_t)hnew;
      }
      // output + publish h1[e-1] -> buf (e-1)&3, per-wave drain + flag
      *(half2*)(ys1 + ((size_t)(e - 1) * 64 + g * 32 + bl) * 1024 + j0 + ug * 2) = hv;
      {
        const char* dst = (const char*)h1f + (size_t)((e + 3) & 3) * 131072
                        + (g * 32 + bl) * 2048 + (j0 + ug * 2) * 2;
        float pv = __builtin_bit_cast(float, hv);
        asm volatile("global_store_dword %0, %1, off sc0 sc1"
                     :: "v"(dst), "v"(pv) : "memory");
      }
      asm volatile("s_waitcnt vmcnt(0)" ::: "memory");
      if (lane == 0) {
        int tv = e;
        const int* dst = flags1 + (wp * 4 + wv) * 4;
        asm volatile("global_store_dword %0, %1, off sc0 sc1"
                     :: "v"(dst), "v"(tv) : "memory");
      }
      __syncthreads();   // hgp reuse protection
    }
  }
}

// ---------------- softmax over 256 vocab (one wave per row) -------------------
__global__ __launch_bounds__(256)
void softmax_kernel(const float* __restrict__ logits, const float* __restrict__ bd,
                    float* __restrict__ out) {
  int w = threadIdx.x >> 6, lane = threadIdx.x & 63;
  int m = blockIdx.x * 4 + w;          // m = s*64 + b
  const float* lrow = logits + (size_t)m * 256;
  float v[4];
  #pragma unroll
  for (int i = 0; i < 4; ++i) v[i] = lrow[lane + i * 64] + bd[lane + i * 64];
  float mx = fmaxf(fmaxf(v[0], v[1]), fmaxf(v[2], v[3]));
  #pragma unroll
  for (int off = 32; off; off >>= 1) mx = fmaxf(mx, __shfl_xor(mx, off));
  float s = 0.f;
  #pragma unroll
  for (int i = 0; i < 4; ++i) { v[i] = __expf(v[i] - mx); s += v[i]; }
  #pragma unroll
  for (int off = 32; off; off >>= 1) s += __shfl_xor(s, off);
  float inv = 1.f / s;
  int b = m & 63, sq = m >> 6;
  float* orow = out + ((size_t)b * 512 + sq) * 256;
  #pragma unroll
  for (int i = 0; i < 4; ++i) orow[lane + i * 64] = v[i] * inv;
}

// ---------------- launch ------------------------------------------------------
extern "C" void kernel_launch(void* const* d_in, const int* in_sizes, int n_in,
                              void* d_out, int out_size, void* d_ws, size_t ws_size,
                              hipStream_t stream) {
  const int*   x   = (const int*)d_in[0];
  const float* emb = (const float*)d_in[1];
  const float* W0  = (const float*)d_in[2];
  const float* U0  = (const float*)d_in[3];
  const float* b0  = (const float*)d_in[4];
  const float* W1  = (const float*)d_in[5];
  const float* U1  = (const float*)d_in[6];
  const float* b1  = (const float*)d_in[7];
  const float* Wd  = (const float*)d_in[8];
  const float* bd  = (const float*)d_in[9];
  float* out = (float*)d_out;
  (void)in_sizes; (void)n_in; (void)out_size; (void)ws_size;

  char* p = (char*)d_ws;
  size_t off = 0;
  auto take = [&](size_t bytes) {
    char* r = p + off;
    off = (off + bytes + 255) & ~(size_t)255;
    return r;
  };
  half_t* T0  = (half_t*)take(3072ull * 1280 * 2);   // [U0;W0]^T
  half_t* T1  = (half_t*)take(3072ull * 2048 * 2);   // [W1;U1]^T
  half_t* WdT = (half_t*)take(256ull * 1024 * 2);
  const size_t H0B = 6ull * 131072, H1B = 4ull * 131072;
  const size_t F0B = 4096, F1B = 8192;
  char* stateblk = take(H0B + H1B + F0B + F1B);
  half_t* h0f   = (half_t*)stateblk;
  half_t* h1f   = (half_t*)(stateblk + H0B);
  int*    flags0 = (int*)(stateblk + H0B + H1B);
  int*    flags1 = (int*)(stateblk + H0B + H1B + F0B);
  half_t* E16 = (half_t*)take(32768ull * 256 * 2);
  half_t* ys1 = (half_t*)take(32768ull * 1024 * 2);
  float* logits = (float*)take(32768ull * 256 * 4);

  // weight transposes fp32->fp16 into concat layouts
  wt_transpose<<<dim3(96, 32), dim3(32, 8), 0, stream>>>(U0, T0, 1024, 3072, 1280, 0);
  wt_transpose<<<dim3(96, 8),  dim3(32, 8), 0, stream>>>(W0, T0, 256,  3072, 1280, 1024);
  wt_transpose<<<dim3(96, 32), dim3(32, 8), 0, stream>>>(W1, T1, 1024, 3072, 2048, 0);
  wt_transpose<<<dim3(96, 32), dim3(32, 8), 0, stream>>>(U1, T1, 1024, 3072, 2048, 1024);
  wt_transpose<<<dim3(8, 32),  dim3(32, 8), 0, stream>>>(Wd, WdT, 1024, 256, 1024, 0);
  embed_kernel<<<4096, 256, 0, stream>>>(x, emb, E16);

  hipFuncSetAttribute((const void*)recur_fused,
                      hipFuncAttributeMaxDynamicSharedMemorySize, 147968);
  hipMemsetAsync(stateblk, 0, H0B + H1B + F0B + F1B, stream);

  recur_fused<<<192, 256, 147968, stream>>>(E16, T0, T1, b0, b1, ys1,
                                            h0f, h1f, flags0, flags1);

  gemm128<<<dim3(2, 256), 256, 0, stream>>>(ys1, WdT, logits, 256, 1024);
  softmax_kernel<<<8192, 256, 0, stream>>>(logits, bd, out);
}

// Round 14
// 3605.923 us; speedup vs baseline: 1.2073x; 1.2073x over previous
//
#include <hip/hip_runtime.h>

typedef _Float16 half_t;
typedef _Float16 half8 __attribute__((ext_vector_type(8)));
typedef _Float16 half4 __attribute__((ext_vector_type(4)));
typedef _Float16 half2 __attribute__((ext_vector_type(2)));
typedef float f32x4 __attribute__((ext_vector_type(4)));
typedef float f32x2 __attribute__((ext_vector_type(2)));

// ---------------- fp32 [K][N] -> fp16 [N rows][ldo] transpose (col offset) ---
__global__ void wt_transpose(const float* __restrict__ in, half_t* __restrict__ outp,
                             int K, int N, int ldo, int co) {
  __shared__ float tile[32][33];
  int nb = blockIdx.x * 32, kb = blockIdx.y * 32;
  int tx = threadIdx.x, ty = threadIdx.y;  // 32 x 8
  for (int i = ty; i < 32; i += 8)
    tile[i][tx] = in[(size_t)(kb + i) * N + nb + tx];
  __syncthreads();
  for (int i = ty; i < 32; i += 8)
    outp[(size_t)(nb + i) * ldo + co + kb + tx] = (half_t)tile[tx][i];
}

// ---------------- embedding gather -> fp16 row-major [m=s*64+b][256] ---------
__global__ __launch_bounds__(256) void embed_kernel(const int* __restrict__ x,
    const float* __restrict__ emb, half_t* __restrict__ E) {
  int g = blockIdx.x * 256 + threadIdx.x;  // 0 .. 32768*32-1
  int m = g >> 5, dp = g & 31;
  int b = m & 63, s = m >> 6;
  int tok = x[b * 512 + s];
  const float* src = emb + (size_t)tok * 256 + dp * 8;
  half8 v;
  #pragma unroll
  for (int i = 0; i < 8; ++i) v[i] = (half_t)src[i];
  *(half8*)(E + (size_t)m * 256 + dp * 8) = v;
}

// ---------------- 128x128 fp16 MFMA GEMM, fp32 C row-major -------------------
__global__ __launch_bounds__(256)
void gemm128(const half_t* __restrict__ A, const half_t* __restrict__ BT,
             float* __restrict__ C, int N, int K) {
  __shared__ __align__(16) half_t As[128 * 32];
  __shared__ __align__(16) half_t Bs[128 * 32];
  const int tid = threadIdx.x;
  const int lane = tid & 63, wid = tid >> 6;
  const int wm = wid >> 1, wn = wid & 1;
  const int l15 = lane & 15, l4 = lane >> 4;
  const int bm = blockIdx.y * 128, bn = blockIdx.x * 128;
  const int srow = tid >> 2;
  const int skb = (tid & 3) * 8;
  f32x4 acc[4][4] = {};

  half8 va[2], vb[2];
  #pragma unroll
  for (int c = 0; c < 2; ++c) {
    int row = c * 64 + srow;
    va[c] = *(const half8*)(A + (size_t)(bm + row) * K + skb);
    vb[c] = *(const half8*)(BT + (size_t)(bn + row) * K + skb);
  }
  for (int k0 = 0; k0 < K; k0 += 32) {
    __syncthreads();
    #pragma unroll
    for (int c = 0; c < 2; ++c) {
      int row = c * 64 + srow;
      *(half8*)(As + row * 32 + skb) = va[c];
      *(half8*)(Bs + row * 32 + skb) = vb[c];
    }
    __syncthreads();
    int k1 = k0 + 32;
    if (k1 < K) {
      #pragma unroll
      for (int c = 0; c < 2; ++c) {
        int row = c * 64 + srow;
        va[c] = *(const half8*)(A + (size_t)(bm + row) * K + k1 + skb);
        vb[c] = *(const half8*)(BT + (size_t)(bn + row) * K + k1 + skb);
      }
    }
    half8 af[4], bf[4];
    #pragma unroll
    for (int mt = 0; mt < 4; ++mt)
      af[mt] = *(const half8*)(As + (wm * 64 + mt * 16 + l15) * 32 + l4 * 8);
    #pragma unroll
    for (int nt = 0; nt < 4; ++nt)
      bf[nt] = *(const half8*)(Bs + (wn * 64 + nt * 16 + l15) * 32 + l4 * 8);
    #pragma unroll
    for (int mt = 0; mt < 4; ++mt)
      #pragma unroll
      for (int nt = 0; nt < 4; ++nt)
        acc[mt][nt] = __builtin_amdgcn_mfma_f32_16x16x32_f16(af[mt], bf[nt], acc[mt][nt], 0, 0, 0);
  }
  #pragma unroll
  for (int mt = 0; mt < 4; ++mt)
    #pragma unroll
    for (int nt = 0; nt < 4; ++nt) {
      int col = bn + wn * 64 + nt * 16 + l15;
      int row0 = bm + wm * 64 + mt * 16 + l4 * 4;
      #pragma unroll
      for (int r = 0; r < 4; ++r)
        C[(size_t)(row0 + r) * N + col] = acc[mt][nt][r];
    }
}

// ---------------- fused 2-layer persistent GRU recurrence --------------------
// EXACT REVERT to the round-12 best-passing kernel (3567 us). Sync protocol:
// flags replicated x4, 16B-strided, WG granularity; sc0/sc1 write-through
// publish + vmcnt(0) drain + barrier + flag store; forced-miss consumer
// loads; cached-flag poll (monotone, deadman 2^14); counted-vmcnt MFMA
// phases; E16 double-buffer; setprio around MFMA.
#define MF(af, bf, a) a = __builtin_amdgcn_mfma_f32_16x16x32_f16(af, bf, a, 0, 0, 0)
#define BC8(x) __builtin_bit_cast(half8, x)
#define GLD4(dst, base, OFS) asm volatile("global_load_dwordx4 %0, %1, off offset:" OFS " sc0 sc1" : "=v"(dst) : "v"(base))
#define GLD4P(dst, base, OFS) asm volatile("global_load_dwordx4 %0, %1, off offset:" OFS : "=v"(dst) : "v"(base))
#define HL8(t, B) GLD4(hrA[t][0],B,"0");GLD4(hrA[t][1],B,"64");GLD4(hrA[t][2],B,"128");GLD4(hrA[t][3],B,"192");GLD4(hrA[t][4],B,"256");GLD4(hrA[t][5],B,"320");GLD4(hrA[t][6],B,"384");GLD4(hrA[t][7],B,"448")
#define HL16(t, B) HL8(t,B);GLD4(hrA[t][8],B,"512");GLD4(hrA[t][9],B,"576");GLD4(hrA[t][10],B,"640");GLD4(hrA[t][11],B,"704");GLD4(hrA[t][12],B,"768");GLD4(hrA[t][13],B,"832");GLD4(hrA[t][14],B,"896");GLD4(hrA[t][15],B,"960")
#define LDH0(u, kt) (*(const half8*)(smem + ((((u) * 2048) + wv * 512 + (kt) * 64 + l4x16) ^ (((u) & 7) << 4))))
#define LDE0(u, kt) (*(const half8*)(smem + 65536 + ((((u) * 512) + wv * 128 + (kt) * 64 + l4x16) ^ (((u) & 7) << 4))))
#define LDH1(kt) (*(const half8*)(smem + ((l15 * 4096 + wv * 1024 + (kt) * 64 + l4x16) ^ ((l15 & 7) << 4))))
#define SB __builtin_amdgcn_sched_barrier(0)

// cached-flag poll: fsav is a persistent per-lane cache of the monotone flag.
// Zero memory ops when already satisfied; divergent reload otherwise.
#define POLLC(fp, tgt, fsav) { int dm_ = 0; \
    while (!__all((fsav) >= (tgt))) { \
      if ((fsav) < (tgt)) \
        asm volatile("global_load_dword %0, %1, off sc0 sc1\n\ts_waitcnt vmcnt(0)" \
                     : "=v"(fsav) : "v"(fp) : "memory"); \
      if (++dm_ > (1 << 14)) break; \
    } }

__global__ __launch_bounds__(256, 1)
void recur_fused(const half_t* __restrict__ E16,  // [32768][256]
                 const half_t* __restrict__ T0,   // [3072][1280] = [U0;W0]^T
                 const half_t* __restrict__ T1,   // [3072][2048] = [W1;U1]^T
                 const float* __restrict__ bias0, // [2][3072]
                 const float* __restrict__ bias1, // [2][3072]
                 half_t* __restrict__ ys1,        // [32768][1024]
                 half_t* __restrict__ h0f,        // [6][64][1024] half
                 half_t* __restrict__ h1f,        // [4][64][1024] half
                 int* __restrict__ flags0,        // [4 rep][64 WG][4] (16B stride)
                 int* __restrict__ flags1) {      // [4 rep][128 WG][4]
  extern __shared__ unsigned char smem[];
  const int tid = threadIdx.x;
  const int lane = tid & 63, wv = tid >> 6;
  const int l15 = lane & 15, l4 = lane >> 4;
  const int l4x16 = l4 * 16;
  const int ug = tid >> 5;          // 0..7
  const int bl = lane & 31;         // batch within group

  if (blockIdx.x < 64) {
    // =================== LAYER 0 ===================
    const int w = blockIdx.x;
    const int g = w >> 5, uslot = w & 31, j0 = uslot * 32;
    float* hgp = (float*)(smem + 81920);   // [4][32][129]

    // stage h-part hh rows (32 units x 1024), XOR-swizzled
    for (int it = 0; it < 16; ++it) {
      int idx = it * 256 + tid;
      int u = idx >> 7, kc = idx & 127;
      int byteoff = (u * 2048 + kc * 16) ^ ((u & 7) << 4);
      *(half8*)(smem + byteoff) =
          *(const half8*)(T0 + (size_t)(2048 + j0 + u) * 1280 + kc * 8);
    }
    // stage e-part hh rows (32 units x 256)
    for (int it = 0; it < 4; ++it) {
      int idx = it * 256 + tid;
      int u = idx >> 5, kc = idx & 31;
      int byteoff = 65536 + ((u * 512 + kc * 16) ^ ((u & 7) << 4));
      *(half8*)(smem + byteoff) =
          *(const half8*)(T0 + (size_t)(2048 + j0 + u) * 1280 + 1024 + kc * 8);
    }
    // pin z,r B-frags: h-part and e-part
    half8 zr[2][2][8], ezr[2][2][2];
    #pragma unroll
    for (int gate = 0; gate < 2; ++gate)
      #pragma unroll
      for (int uh = 0; uh < 2; ++uh) {
        const half_t* row = T0 + (size_t)(gate * 1024 + j0 + uh * 16 + l15) * 1280;
        #pragma unroll
        for (int kt = 0; kt < 8; ++kt)
          zr[gate][uh][kt] = *(const half8*)(row + wv * 256 + kt * 32 + l4 * 8);
        #pragma unroll
        for (int kt = 0; kt < 2; ++kt)
          ezr[gate][uh][kt] = *(const half8*)(row + 1024 + wv * 64 + kt * 32 + l4 * 8);
      }
    // gate constants + master h in regs
    float bz[4], br[4], bhr[4], bxh[4], hM[4];
    #pragma unroll
    for (int q = 0; q < 4; ++q) {
      int j = j0 + ug * 4 + q;
      bz[q]  = bias0[j]        + bias0[3072 + j];
      br[q]  = bias0[1024 + j] + bias0[4096 + j];
      bxh[q] = bias0[2048 + j];
      bhr[q] = bias0[5120 + j];
      hM[q] = 0.f;
    }
    // poll addresses: lanes<32 -> own-group flags0 replica wv (data dep);
    // lanes>=32 -> flags1 quarter (WAR slack-5)
    const int* fp = (lane < 32)
        ? flags0 + (wv * 64 + g * 32 + bl) * 4
        : flags1 + (wv * 128 + g * 64 + wv * 16 + (lane & 15)) * 4;
    int fsav0 = 0;   // cached flag value (monotone)
    // E16 prefetch for epoch 0 (plain loads; double-buffered across epochs)
    f32x4 erC[2][2], erN[2][2];
    {
      const char* eb0 = (const char*)E16 + (size_t)(g * 32 + l15) * 512 + wv * 128 + l4x16;
      const char* eb1 = eb0 + 8192;
      GLD4P(erC[0][0], eb0, "0"); GLD4P(erC[0][1], eb0, "64");
      GLD4P(erC[1][0], eb1, "0"); GLD4P(erC[1][1], eb1, "64");
    }
    asm volatile("s_waitcnt vmcnt(0)" ::: "memory");
    __syncthreads();

    for (int e = 0; e < 512; ++e) {
      POLLC(fp, ((lane < 32) ? e : (e - 5)), fsav0);
      // A loads: h0[e-1] (buf (e+5)%6, sc forced-miss); E16[e] already in erC.
      // E16[e+1] prefetch issued after the h loads (newest in vmcnt order).
      f32x4 hrA[2][8];
      {
        const char* hbb = (const char*)h0f + (size_t)((e + 5) % 6) * 131072;
        const char* hb0 = hbb + (g * 32 + l15) * 2048 + wv * 512 + l4x16;
        const char* hb1 = hb0 + 32768;
        HL8(0, hb0); HL8(1, hb1);
        int en = (e < 511) ? e + 1 : e;
        const char* eb0 = (const char*)E16 +
            (size_t)(en * 64 + g * 32 + l15) * 512 + wv * 128 + l4x16;
        const char* eb1 = eb0 + 8192;
        GLD4P(erN[0][0], eb0, "0"); GLD4P(erN[0][1], eb0, "64");
        GLD4P(erN[1][0], eb1, "0"); GLD4P(erN[1][1], eb1, "64");
      }
      // ---- MFMA phase 1: A-tile 0 (oldest 8 loads; 12 in flight allowed) ----
      asm volatile("s_waitcnt vmcnt(12)" ::: "memory"); SB;
      __builtin_amdgcn_s_setprio(1);
      f32x4 acc[2][8] = {};
      #pragma unroll
      for (int kt = 0; kt < 8; ++kt) {
        half8 af0 = BC8(hrA[0][kt]);
        MF(af0, zr[0][0][kt], acc[0][0]);
        MF(af0, zr[0][1][kt], acc[0][1]);
        MF(af0, zr[1][0][kt], acc[0][2]);
        MF(af0, zr[1][1][kt], acc[0][3]);
        half8 bh0 = LDH0(l15, kt), bh1 = LDH0(16 + l15, kt);
        MF(af0, bh0, acc[0][4]);
        MF(af0, bh1, acc[0][5]);
      }
      // ---- MFMA phase 2: A-tile 1 (all h loads done; erN may be in flight) --
      asm volatile("s_waitcnt vmcnt(4)" ::: "memory"); SB;
      #pragma unroll
      for (int kt = 0; kt < 8; ++kt) {
        half8 af1 = BC8(hrA[1][kt]);
        MF(af1, zr[0][0][kt], acc[1][0]);
        MF(af1, zr[0][1][kt], acc[1][1]);
        MF(af1, zr[1][0][kt], acc[1][2]);
        MF(af1, zr[1][1][kt], acc[1][3]);
        half8 bh0 = LDH0(l15, kt), bh1 = LDH0(16 + l15, kt);
        MF(af1, bh0, acc[1][4]);
        MF(af1, bh1, acc[1][5]);
      }
      // ---- MFMA phase 3: e-part (erC from regs; drain erN for rotation) ----
      asm volatile("s_waitcnt vmcnt(0)" ::: "memory"); SB;
      #pragma unroll
      for (int kt = 0; kt < 2; ++kt) {
        half8 af0 = BC8(erC[0][kt]), af1 = BC8(erC[1][kt]);
        MF(af0, ezr[0][0][kt], acc[0][0]); MF(af1, ezr[0][0][kt], acc[1][0]);
        MF(af0, ezr[0][1][kt], acc[0][1]); MF(af1, ezr[0][1][kt], acc[1][1]);
        MF(af0, ezr[1][0][kt], acc[0][2]); MF(af1, ezr[1][0][kt], acc[1][2]);
        MF(af0, ezr[1][1][kt], acc[0][3]); MF(af1, ezr[1][1][kt], acc[1][3]);
        half8 be0 = LDE0(l15, kt), be1 = LDE0(16 + l15, kt);
        MF(af0, be0, acc[0][6]); MF(af1, be0, acc[1][6]);
        MF(af0, be1, acc[0][7]); MF(af1, be1, acc[1][7]);
      }
      __builtin_amdgcn_s_setprio(0);
      // scatter partials: rows = kv*32 + batch, cols: z0..31|r|hh_h|hh_e
      #pragma unroll
      for (int m = 0; m < 2; ++m)
        #pragma unroll
        for (int n = 0; n < 8; ++n) {
          int colb = (n < 6) ? ((n >> 1) * 32 + (n & 1) * 16) : (96 + (n & 1) * 16);
          #pragma unroll
          for (int r = 0; r < 4; ++r)
            hgp[(wv * 32 + m * 16 + l4 * 4 + r) * 129 + colb + l15] = acc[m][n][r];
        }
      __syncthreads();
      // combine (thread = batch bl x 4 units)
      half4 hv;
      #pragma unroll
      for (int q = 0; q < 4; ++q) {
        int c = ug * 4 + q;
        float hz = 0.f, hr = 0.f, hhh = 0.f, xh = 0.f;
        #pragma unroll
        for (int kv = 0; kv < 4; ++kv) {
          const float* rowp = hgp + (kv * 32 + bl) * 129 + c;
          hz += rowp[0]; hr += rowp[32]; hhh += rowp[64]; xh += rowp[96];
        }
        float z = 1.f / (1.f + __expf(-(hz + bz[q])));
        float r = 1.f / (1.f + __expf(-(hr + br[q])));
        float targ = xh + bxh[q] + r * (hhh + bhr[q]);
        float hh = 1.f - 2.f / (1.f + __expf(2.f * targ));
        float hnew = z * hM[q] + (1.f - z) * hh;
        hM[q] = hnew;
        hv[q] = (half_t)hnew;
      }
      // rotate E16 buffers (erN drained at phase-3 vmcnt(0))
      #pragma unroll
      for (int a = 0; a < 2; ++a)
        #pragma unroll
        for (int b2 = 0; b2 < 2; ++b2) erC[a][b2] = erN[a][b2];
      // publish h0[e] -> buf e%6
      {
        const char* dst = (const char*)h0f + (size_t)(e % 6) * 131072
                        + (g * 32 + bl) * 2048 + (j0 + ug * 4) * 2;
        f32x2 pv = __builtin_bit_cast(f32x2, hv);
        asm volatile("global_store_dwordx2 %0, %1, off sc0 sc1"
                     :: "v"(dst), "v"(pv) : "memory");
      }
      asm volatile("s_waitcnt vmcnt(0)" ::: "memory");
      __syncthreads();
      if (tid < 4) {
        int tv = e + 1;
        const int* dst = flags0 + (tid * 64 + w) * 4;
        asm volatile("global_store_dword %0, %1, off sc0 sc1"
                     :: "v"(dst), "v"(tv) : "memory");
      }
    }
  } else {
    // =================== LAYER 1 ===================
    const int wp = blockIdx.x - 64;
    const int g = wp >> 6, uslot = wp & 63, j0 = uslot * 16;
    float* hgp = (float*)(smem + 65536);   // [4][32][65]

    // stage hh rows (16 units x 2048), XOR-swizzled
    for (int it = 0; it < 16; ++it) {
      int idx = it * 256 + tid;
      int u = idx >> 8, kc = idx & 255;
      int byteoff = (u * 4096 + kc * 16) ^ ((u & 7) << 4);
      *(half8*)(smem + byteoff) =
          *(const half8*)(T1 + (size_t)(2048 + j0 + u) * 2048 + kc * 8);
    }
    // pin z,r B-frags over this wave's 512-k slice
    half8 zr1[2][16];
    #pragma unroll
    for (int gate = 0; gate < 2; ++gate) {
      const half_t* row = T1 + (size_t)(gate * 1024 + j0 + l15) * 2048 + wv * 512;
      #pragma unroll
      for (int kt = 0; kt < 16; ++kt)
        zr1[gate][kt] = *(const half8*)(row + kt * 32 + l4 * 8);
    }
    float bz[2], br[2], bhr[2], bxh[2], hM[2];
    #pragma unroll
    for (int q = 0; q < 2; ++q) {
      int j = j0 + ug * 2 + q;
      bz[q]  = bias1[j]        + bias1[3072 + j];
      br[q]  = bias1[1024 + j] + bias1[4096 + j];
      bxh[q] = bias1[2048 + j];
      bhr[q] = bias1[5120 + j];
      hM[q] = 0.f;
    }
    // poll addresses: waves 0,1 -> flags0 (replicas 0,1); waves 2,3 -> flags1
    const int* fp = (wv < 2)
        ? flags0 + (wv * 64 + g * 32 + bl) * 4
        : flags1 + (wv * 128 + g * 64 + lane) * 4;
    int fsav1 = 0;
    __syncthreads();

    for (int e = 1; e <= 512; ++e) {
      POLLC(fp, ((wv < 2) ? e : (e - 1)), fsav1);
      // A loads: waves 0,1 from h0[e-1] (buf (e+5)%6); waves 2,3 from h1[e-2]
      f32x4 hrA[2][16];
      {
        const char* fb = (wv < 2)
            ? (const char*)h0f + (size_t)((e + 5) % 6) * 131072
            : (const char*)h1f + (size_t)((e + 2) & 3) * 131072;
        const char* b0 = fb + (g * 32 + l15) * 2048 + (wv & 1) * 1024 + l4x16;
        const char* b1 = b0 + 32768;
        HL16(0, b0); HL16(1, b1);
      }
      // ---- MFMA phase 1: A-tile 0 (oldest 16 loads) ----
      asm volatile("s_waitcnt vmcnt(16)" ::: "memory"); SB;
      __builtin_amdgcn_s_setprio(1);
      f32x4 acc[2][3] = {};
      #pragma unroll
      for (int kt = 0; kt < 16; ++kt) {
        half8 af0 = BC8(hrA[0][kt]);
        MF(af0, zr1[0][kt], acc[0][0]);
        MF(af0, zr1[1][kt], acc[0][1]);
        half8 bh = LDH1(kt);
        MF(af0, bh, acc[0][2]);
      }
      // ---- MFMA phase 2: A-tile 1 ----
      asm volatile("s_waitcnt vmcnt(0)" ::: "memory"); SB;
      #pragma unroll
      for (int kt = 0; kt < 16; ++kt) {
        half8 af1 = BC8(hrA[1][kt]);
        MF(af1, zr1[0][kt], acc[1][0]);
        MF(af1, zr1[1][kt], acc[1][1]);
        half8 bh = LDH1(kt);
        MF(af1, bh, acc[1][2]);
      }
      __builtin_amdgcn_s_setprio(0);
      // scatter: cols z:0..15, r:16..31, hh_h:32..47 (wv>=2), hh_x:48..63 (wv<2)
      {
        int hhcol = (wv < 2) ? 48 : 32;
        #pragma unroll
        for (int m = 0; m < 2; ++m)
          #pragma unroll
          for (int r = 0; r < 4; ++r) {
            int row = (wv * 32 + m * 16 + l4 * 4 + r) * 65;
            hgp[row + l15]        = acc[m][0][r];
            hgp[row + 16 + l15]   = acc[m][1][r];
            hgp[row + hhcol + l15] = acc[m][2][r];
          }
      }
      __syncthreads();
      // combine (thread = batch bl x 2 units)
      half2 hv;
      #pragma unroll
      for (int q = 0; q < 2; ++q) {
        int c = ug * 2 + q;
        float hz = 0.f, hr = 0.f;
        #pragma unroll
        for (int kv = 0; kv < 4; ++kv) {
          const float* rowp = hgp + (kv * 32 + bl) * 65 + c;
          hz += rowp[0]; hr += rowp[16];
        }
        float hhh = hgp[(2 * 32 + bl) * 65 + 32 + c] + hgp[(3 * 32 + bl) * 65 + 32 + c];
        float xh  = hgp[(0 * 32 + bl) * 65 + 48 + c] + hgp[(1 * 32 + bl) * 65 + 48 + c];
        float z = 1.f / (1.f + __expf(-(hz + bz[q])));
        float r = 1.f / (1.f + __expf(-(hr + br[q])));
        float targ = xh + bxh[q] + r * (hhh + bhr[q]);
        float hh = 1.f - 2.f / (1.f + __expf(2.f * targ));
        float hnew = z * hM[q] + (1.f - z) * hh;
        hM[q] = hnew;
        hv[q] = (half_t)hnew;
      }
      // output + publish h1[e-1] -> buf (e-1)&3
      *(half2*)(ys1 + ((size_t)(e - 1) * 64 + g * 32 + bl) * 1024 + j0 + ug * 2) = hv;
      {
        const char* dst = (const char*)h1f + (size_t)((e + 3) & 3) * 131072
                        + (g * 32 + bl) * 2048 + (j0 + ug * 2) * 2;
        float pv = __builtin_bit_cast(float, hv);
        asm volatile("global_store_dword %0, %1, off sc0 sc1"
                     :: "v"(dst), "v"(pv) : "memory");
      }
      asm volatile("s_waitcnt vmcnt(0)" ::: "memory");
      __syncthreads();
      if (tid < 4) {
        int tv = e;
        const int* dst = flags1 + (tid * 128 + wp) * 4;
        asm volatile("global_store_dword %0, %1, off sc0 sc1"
                     :: "v"(dst), "v"(tv) : "memory");
      }
    }
  }
}

// ---------------- softmax over 256 vocab (one wave per row) -------------------
__global__ __launch_bounds__(256)
void softmax_kernel(const float* __restrict__ logits, const float* __restrict__ bd,
                    float* __restrict__ out) {
  int w = threadIdx.x >> 6, lane = threadIdx.x & 63;
  int m = blockIdx.x * 4 + w;          // m = s*64 + b
  const float* lrow = logits + (size_t)m * 256;
  float v[4];
  #pragma unroll
  for (int i = 0; i < 4; ++i) v[i] = lrow[lane + i * 64] + bd[lane + i * 64];
  float mx = fmaxf(fmaxf(v[0], v[1]), fmaxf(v[2], v[3]));
  #pragma unroll
  for (int off = 32; off; off >>= 1) mx = fmaxf(mx, __shfl_xor(mx, off));
  float s = 0.f;
  #pragma unroll
  for (int i = 0; i < 4; ++i) { v[i] = __expf(v[i] - mx); s += v[i]; }
  #pragma unroll
  for (int off = 32; off; off >>= 1) s += __shfl_xor(s, off);
  float inv = 1.f / s;
  int b = m & 63, sq = m >> 6;
  float* orow = out + ((size_t)b * 512 + sq) * 256;
  #pragma unroll
  for (int i = 0; i < 4; ++i) orow[lane + i * 64] = v[i] * inv;
}

// ---------------- launch ------------------------------------------------------
extern "C" void kernel_launch(void* const* d_in, const int* in_sizes, int n_in,
                              void* d_out, int out_size, void* d_ws, size_t ws_size,
                              hipStream_t stream) {
  const int*   x   = (const int*)d_in[0];
  const float* emb = (const float*)d_in[1];
  const float* W0  = (const float*)d_in[2];
  const float* U0  = (const float*)d_in[3];
  const float* b0  = (const float*)d_in[4];
  const float* W1  = (const float*)d_in[5];
  const float* U1  = (const float*)d_in[6];
  const float* b1  = (const float*)d_in[7];
  const float* Wd  = (const float*)d_in[8];
  const float* bd  = (const float*)d_in[9];
  float* out = (float*)d_out;
  (void)in_sizes; (void)n_in; (void)out_size; (void)ws_size;

  char* p = (char*)d_ws;
  size_t off = 0;
  auto take = [&](size_t bytes) {
    char* r = p + off;
    off = (off + bytes + 255) & ~(size_t)255;
    return r;
  };
  half_t* T0  = (half_t*)take(3072ull * 1280 * 2);   // [U0;W0]^T
  half_t* T1  = (half_t*)take(3072ull * 2048 * 2);   // [W1;U1]^T
  half_t* WdT = (half_t*)take(256ull * 1024 * 2);
  const size_t H0B = 6ull * 131072, H1B = 4ull * 131072;
  const size_t F0B = 4096, F1B = 8192;
  char* stateblk = take(H0B + H1B + F0B + F1B);
  half_t* h0f   = (half_t*)stateblk;
  half_t* h1f   = (half_t*)(stateblk + H0B);
  int*    flags0 = (int*)(stateblk + H0B + H1B);
  int*    flags1 = (int*)(stateblk + H0B + H1B + F0B);
  half_t* E16 = (half_t*)take(32768ull * 256 * 2);
  half_t* ys1 = (half_t*)take(32768ull * 1024 * 2);
  float* logits = (float*)take(32768ull * 256 * 4);

  // weight transposes fp32->fp16 into concat layouts
  wt_transpose<<<dim3(96, 32), dim3(32, 8), 0, stream>>>(U0, T0, 1024, 3072, 1280, 0);
  wt_transpose<<<dim3(96, 8),  dim3(32, 8), 0, stream>>>(W0, T0, 256,  3072, 1280, 1024);
  wt_transpose<<<dim3(96, 32), dim3(32, 8), 0, stream>>>(W1, T1, 1024, 3072, 2048, 0);
  wt_transpose<<<dim3(96, 32), dim3(32, 8), 0, stream>>>(U1, T1, 1024, 3072, 2048, 1024);
  wt_transpose<<<dim3(8, 32),  dim3(32, 8), 0, stream>>>(Wd, WdT, 1024, 256, 1024, 0);
  embed_kernel<<<4096, 256, 0, stream>>>(x, emb, E16);

  hipFuncSetAttribute((const void*)recur_fused,
                      hipFuncAttributeMaxDynamicSharedMemorySize, 147968);
  hipMemsetAsync(stateblk, 0, H0B + H1B + F0B + F1B, stream);

  recur_fused<<<192, 256, 147968, stream>>>(E16, T0, T1, b0, b1, ys1,
                                            h0f, h1f, flags0, flags1);

  gemm128<<<dim3(2, 256), 256, 0, stream>>>(ys1, WdT, logits, 256, 1024);
  softmax_kernel<<<8192, 256, 0, stream>>>(logits, bd, out);
}